// Round 6
// baseline (2081.104 us; speedup 1.0000x reference)
//
#include <hip/hip_runtime.h>
#include <hip/hip_bf16.h>

static constexpr int N_ = 50000;
static constexpr int E_ = 800000;
static constexpr int CAP = 128;   // per-wave LDS edge cache (max degree fast-path)

__device__ __forceinline__ float fcomp(float4 v, int t) {
  // t is a compile-time constant after unrolling -> folds to a register pick
  return t == 0 ? v.x : t == 1 ? v.y : t == 2 ? v.z : v.w;
}

// ---------------- CSR build ----------------
__global__ void k_hist(const int* __restrict__ ei, int* __restrict__ deg) {
  int e = blockIdx.x * blockDim.x + threadIdx.x;
  if (e < E_) atomicAdd(&deg[ei[E_ + e]], 1);
}

__global__ __launch_bounds__(1024) void k_scan_blk(const int* __restrict__ deg,
                                                   int* __restrict__ off,
                                                   int* __restrict__ bsum) {
  __shared__ int sm[1024];
  int t = threadIdx.x;
  int i = blockIdx.x * 1024 + t;
  int v = (i < N_) ? deg[i] : 0;
  sm[t] = v;
  __syncthreads();
  for (int s = 1; s < 1024; s <<= 1) {
    int u = (t >= s) ? sm[t - s] : 0;
    __syncthreads();
    sm[t] += u;
    __syncthreads();
  }
  if (i < N_) off[i] = sm[t] - v;
  if (t == 1023) bsum[blockIdx.x] = sm[t];
}

__global__ void k_scan_top(int* __restrict__ bsum, int nb) {
  int t = threadIdx.x;  // 64
  int v = (t < nb) ? bsum[t] : 0;
  int orig = v;
  for (int s = 1; s < 64; s <<= 1) {
    int u = __shfl_up(v, s);
    if (t >= s) v += u;
  }
  if (t < nb) bsum[t] = v - orig;
}

__global__ void k_scan_add(int* __restrict__ off, const int* __restrict__ bsum,
                           int* __restrict__ cur) {
  int i = blockIdx.x * blockDim.x + threadIdx.x;
  if (i < N_) {
    int o = off[i] + bsum[i >> 10];
    off[i] = o;
    cur[i] = o;
  }
  if (i == 0) off[N_] = E_;
}

__global__ void k_scatter(const int* __restrict__ ei, int* __restrict__ cursor,
                          int2* __restrict__ csr_es) {
  int e = blockIdx.x * blockDim.x + threadIdx.x;
  if (e < E_) {
    int s = ei[e];
    int d = ei[E_ + e];
    int p = atomicAdd(&cursor[d], 1);
    csr_es[p] = make_int2(e, s);
  }
}

// ---------------- Encoder input gather: IN[N,24] (col 23 = 0) ----------------
__global__ void k_gather(const float* __restrict__ x, const int* __restrict__ ntype,
                         const int* __restrict__ sid,
                         const float* __restrict__ temb, const float* __restrict__ semb,
                         float* __restrict__ IN) {
  int v = blockIdx.x * 256 + threadIdx.x;
  if (v >= N_) return;
  float in[24];
#pragma unroll
  for (int i = 0; i < 7; ++i) in[i] = x[v * 7 + i];
  int nt = ntype[v], sd = sid[v];
#pragma unroll
  for (int i = 0; i < 8; ++i) in[7 + i] = temb[nt * 8 + i];
#pragma unroll
  for (int i = 0; i < 8; ++i) in[15 + i] = semb[sd * 8 + i];
  in[23] = 0.f;
#pragma unroll
  for (int q = 0; q < 6; ++q)
    *(float4*)(IN + (size_t)v * 24 + q * 4) =
        make_float4(in[q * 4], in[q * 4 + 1], in[q * 4 + 2], in[q * 4 + 3]);
}

// ---------------- Tiled GEMM: C[M,64] = act(A[M,K] @ W[K,64] + b) ----------------
// Block: 256 thr = 8 cols x 32 rows; 128 nodes/block; thread tile 4 nodes x 8 outs.
// NOTE: no address-taken locals anywhere -- everything must stay in VGPRs.
template <int KPAD, bool RELU, bool ACC>
__global__ __launch_bounds__(256) void k_gemm(
    const float* __restrict__ A, int lda, int Kreal,
    const float* __restrict__ W, int ldw,
    const float* __restrict__ bias,
    float* __restrict__ C, int ldc) {
  constexpr int PITCH = KPAD + 4;
  constexpr int KQ = KPAD / 4;
  __shared__ float At[128 * PITCH];
  __shared__ float Wt[KPAD * 64];
  int tid = threadIdx.x;
  int nb = blockIdx.x * 128;
  // stage W (zero rows k >= Kreal)
  for (int idx = tid; idx < KPAD * 16; idx += 256) {
    int k = idx >> 4, jq = idx & 15;
    float4 v = (k < Kreal) ? *(const float4*)(W + (size_t)k * ldw + jq * 4)
                           : make_float4(0.f, 0.f, 0.f, 0.f);
    *(float4*)(Wt + k * 64 + jq * 4) = v;
  }
  // stage A (zero rows past M)
  for (int idx = tid; idx < 128 * KQ; idx += 256) {
    int r = idx / KQ, kq = idx % KQ;
    int node = nb + r;
    float4 v = (node < N_) ? *(const float4*)(A + (size_t)node * lda + kq * 4)
                           : make_float4(0.f, 0.f, 0.f, 0.f);
    *(float4*)(At + r * PITCH + kq * 4) = v;
  }
  __syncthreads();
  int col = tid & 7, row = tid >> 3;
  int j0 = col * 8, n0 = row * 4;
  float4 b0 = *(const float4*)(bias + j0);
  float4 b1 = *(const float4*)(bias + j0 + 4);
  float acc[4][8];
#pragma unroll
  for (int i = 0; i < 4; ++i) {
    acc[i][0] = b0.x; acc[i][1] = b0.y; acc[i][2] = b0.z; acc[i][3] = b0.w;
    acc[i][4] = b1.x; acc[i][5] = b1.y; acc[i][6] = b1.z; acc[i][7] = b1.w;
  }
#pragma unroll
  for (int kg = 0; kg < KQ; ++kg) {
    float4 a0 = *(const float4*)(At + (n0 + 0) * PITCH + kg * 4);
    float4 a1 = *(const float4*)(At + (n0 + 1) * PITCH + kg * 4);
    float4 a2 = *(const float4*)(At + (n0 + 2) * PITCH + kg * 4);
    float4 a3 = *(const float4*)(At + (n0 + 3) * PITCH + kg * 4);
#pragma unroll
    for (int t = 0; t < 4; ++t) {
      float4 w0 = *(const float4*)(Wt + (kg * 4 + t) * 64 + j0);
      float4 w1 = *(const float4*)(Wt + (kg * 4 + t) * 64 + j0 + 4);
      float av0 = fcomp(a0, t), av1 = fcomp(a1, t), av2 = fcomp(a2, t), av3 = fcomp(a3, t);
      acc[0][0] = fmaf(av0, w0.x, acc[0][0]); acc[0][1] = fmaf(av0, w0.y, acc[0][1]);
      acc[0][2] = fmaf(av0, w0.z, acc[0][2]); acc[0][3] = fmaf(av0, w0.w, acc[0][3]);
      acc[0][4] = fmaf(av0, w1.x, acc[0][4]); acc[0][5] = fmaf(av0, w1.y, acc[0][5]);
      acc[0][6] = fmaf(av0, w1.z, acc[0][6]); acc[0][7] = fmaf(av0, w1.w, acc[0][7]);
      acc[1][0] = fmaf(av1, w0.x, acc[1][0]); acc[1][1] = fmaf(av1, w0.y, acc[1][1]);
      acc[1][2] = fmaf(av1, w0.z, acc[1][2]); acc[1][3] = fmaf(av1, w0.w, acc[1][3]);
      acc[1][4] = fmaf(av1, w1.x, acc[1][4]); acc[1][5] = fmaf(av1, w1.y, acc[1][5]);
      acc[1][6] = fmaf(av1, w1.z, acc[1][6]); acc[1][7] = fmaf(av1, w1.w, acc[1][7]);
      acc[2][0] = fmaf(av2, w0.x, acc[2][0]); acc[2][1] = fmaf(av2, w0.y, acc[2][1]);
      acc[2][2] = fmaf(av2, w0.z, acc[2][2]); acc[2][3] = fmaf(av2, w0.w, acc[2][3]);
      acc[2][4] = fmaf(av2, w1.x, acc[2][4]); acc[2][5] = fmaf(av2, w1.y, acc[2][5]);
      acc[2][6] = fmaf(av2, w1.z, acc[2][6]); acc[2][7] = fmaf(av2, w1.w, acc[2][7]);
      acc[3][0] = fmaf(av3, w0.x, acc[3][0]); acc[3][1] = fmaf(av3, w0.y, acc[3][1]);
      acc[3][2] = fmaf(av3, w0.z, acc[3][2]); acc[3][3] = fmaf(av3, w0.w, acc[3][3]);
      acc[3][4] = fmaf(av3, w1.x, acc[3][4]); acc[3][5] = fmaf(av3, w1.y, acc[3][5]);
      acc[3][6] = fmaf(av3, w1.z, acc[3][6]); acc[3][7] = fmaf(av3, w1.w, acc[3][7]);
    }
  }
#pragma unroll
  for (int i = 0; i < 4; ++i) {
    int node = nb + n0 + i;
    if (node < N_) {
      float* cp = C + (size_t)node * ldc + j0;
      float o0 = acc[i][0], o1 = acc[i][1], o2 = acc[i][2], o3 = acc[i][3];
      float o4 = acc[i][4], o5 = acc[i][5], o6 = acc[i][6], o7 = acc[i][7];
      if (RELU) {
        o0 = fmaxf(o0, 0.f); o1 = fmaxf(o1, 0.f); o2 = fmaxf(o2, 0.f); o3 = fmaxf(o3, 0.f);
        o4 = fmaxf(o4, 0.f); o5 = fmaxf(o5, 0.f); o6 = fmaxf(o6, 0.f); o7 = fmaxf(o7, 0.f);
      }
      if (ACC) {
        float4 c0 = *(const float4*)cp;
        float4 c1 = *(const float4*)(cp + 4);
        o0 += c0.x; o1 += c0.y; o2 += c0.z; o3 += c0.w;
        o4 += c1.x; o5 += c1.y; o6 += c1.z; o7 += c1.w;
      }
      *(float4*)cp = make_float4(o0, o1, o2, o3);
      *(float4*)(cp + 4) = make_float4(o4, o5, o6, o7);
    }
  }
}

// ---------------- Fused GAT: 4 edges x 16 lanes per wave ----------------
template <bool RELU>
__global__ __launch_bounds__(256) void k_fused(
    const int* __restrict__ off, const int2* __restrict__ csr_es,
    const float* __restrict__ eattr,
    const float* __restrict__ xl, const float* __restrict__ xr,
    const float* __restrict__ we, const float* __restrict__ att,
    const float* __restrict__ bias,
    float* __restrict__ hout, float* __restrict__ alpha) {
  __shared__ float exbuf[4][CAP * 4];
  __shared__ int ebuf[4][CAP];
  int tid = threadIdx.x;
  int lane = tid & 63, wv = tid >> 6;
  int slot = lane >> 4;       // edge slot 0..3
  int q = lane & 15;          // channel quad: channels q*4 .. q*4+3
  int head = q >> 2;
  int sb = slot << 4;
  float wef[6][4], att4[4], b4[4];
#pragma unroll
  for (int i = 0; i < 6; ++i)
#pragma unroll
    for (int r = 0; r < 4; ++r) wef[i][r] = we[i * 64 + q * 4 + r];
#pragma unroll
  for (int r = 0; r < 4; ++r) { att4[r] = att[q * 4 + r]; b4[r] = bias[q * 4 + r]; }

  int wid = (blockIdx.x * blockDim.x + tid) >> 6;
  int nw = (gridDim.x * blockDim.x) >> 6;
  for (int v = wid; v < N_; v += nw) {
    int p0 = off[v], p1 = off[v + 1];
    int cnt = p1 - p0;
    float4 xr4 = *(const float4*)(xr + (size_t)v * 64 + q * 4);
    float num0 = 0.f, num1 = 0.f, num2 = 0.f, num3 = 0.f, den = 0.f;
    int p = p0 + slot;
    int2 es = (p < p1) ? csr_es[p] : make_int2(0, 0);
    for (int base = 0; base < cnt; base += 4) {
      bool valid = (p0 + base + slot) < p1;
      int e = es.x, s = es.y;
      int pn = p0 + base + 4 + slot;
      int2 esn = (pn < p1) ? csr_es[pn] : make_int2(0, 0);
      float ea = (valid && q < 6) ? eattr[(size_t)e * 6 + q] : 0.f;
      float4 xls = valid ? *(const float4*)(xl + (size_t)s * 64 + q * 4)
                         : make_float4(0.f, 0.f, 0.f, 0.f);
      float m0 = xls.x + xr4.x, m1 = xls.y + xr4.y, m2 = xls.z + xr4.z, m3 = xls.w + xr4.w;
#pragma unroll
      for (int i = 0; i < 6; ++i) {
        float eai = __shfl(ea, sb + i);
        m0 = fmaf(eai, wef[i][0], m0);
        m1 = fmaf(eai, wef[i][1], m1);
        m2 = fmaf(eai, wef[i][2], m2);
        m3 = fmaf(eai, wef[i][3], m3);
      }
      m0 = (m0 > 0.f) ? m0 : 0.2f * m0;
      m1 = (m1 > 0.f) ? m1 : 0.2f * m1;
      m2 = (m2 > 0.f) ? m2 : 0.2f * m2;
      m3 = (m3 > 0.f) ? m3 : 0.2f * m3;
      float t = m0 * att4[0];
      t = fmaf(m1, att4[1], t);
      t = fmaf(m2, att4[2], t);
      t = fmaf(m3, att4[3], t);
      t += __shfl_xor(t, 1);
      t += __shfl_xor(t, 2);
      float ex = valid ? __expf(t) : 0.f;
      den += ex;
      num0 = fmaf(xls.x, ex, num0);
      num1 = fmaf(xls.y, ex, num1);
      num2 = fmaf(xls.z, ex, num2);
      num3 = fmaf(xls.w, ex, num3);
      int idx = base + slot;
      if (valid && idx < CAP) {
        if ((lane & 3) == 0) exbuf[wv][idx * 4 + head] = ex;
        if (q == 0) ebuf[wv][idx] = e;
      }
      es = esn;
    }
    num0 += __shfl_xor(num0, 16); num0 += __shfl_xor(num0, 32);
    num1 += __shfl_xor(num1, 16); num1 += __shfl_xor(num1, 32);
    num2 += __shfl_xor(num2, 16); num2 += __shfl_xor(num2, 32);
    num3 += __shfl_xor(num3, 16); num3 += __shfl_xor(num3, 32);
    den  += __shfl_xor(den, 16);  den  += __shfl_xor(den, 32);
    float dinv = 1.f / (den + 1e-16f);
    float o0 = fmaf(num0, dinv, b4[0]);
    float o1 = fmaf(num1, dinv, b4[1]);
    float o2 = fmaf(num2, dinv, b4[2]);
    float o3 = fmaf(num3, dinv, b4[3]);
    if (RELU) {
      o0 = fmaxf(o0, 0.f); o1 = fmaxf(o1, 0.f); o2 = fmaxf(o2, 0.f); o3 = fmaxf(o3, 0.f);
    }
    if (slot == 0)
      *(float4*)(hout + (size_t)v * 64 + q * 4) = make_float4(o0, o1, o2, o3);
    float dh = __shfl(dinv, (lane & 3) << 2);
    if (cnt <= CAP) {
      for (int base2 = 0; base2 < cnt; base2 += 16) {
        int idx = base2 + (lane >> 2);
        if (idx < cnt) {
          float exv = exbuf[wv][idx * 4 + (lane & 3)];
          int e = ebuf[wv][idx];
          alpha[(size_t)e * 4 + (lane & 3)] = exv * dh;
        }
      }
    } else {
      for (int pp = p0; pp < p1; ++pp) {
        int2 es2 = csr_es[pp];
        int e = es2.x, s = es2.y;
        float ea = (q < 6) ? eattr[(size_t)e * 6 + q] : 0.f;
        float4 xls = *(const float4*)(xl + (size_t)s * 64 + q * 4);
        float m0 = xls.x + xr4.x, m1 = xls.y + xr4.y, m2 = xls.z + xr4.z, m3 = xls.w + xr4.w;
#pragma unroll
        for (int i = 0; i < 6; ++i) {
          float eai = __shfl(ea, i);
          m0 = fmaf(eai, wef[i][0], m0);
          m1 = fmaf(eai, wef[i][1], m1);
          m2 = fmaf(eai, wef[i][2], m2);
          m3 = fmaf(eai, wef[i][3], m3);
        }
        m0 = (m0 > 0.f) ? m0 : 0.2f * m0;
        m1 = (m1 > 0.f) ? m1 : 0.2f * m1;
        m2 = (m2 > 0.f) ? m2 : 0.2f * m2;
        m3 = (m3 > 0.f) ? m3 : 0.2f * m3;
        float t = m0 * att4[0];
        t = fmaf(m1, att4[1], t);
        t = fmaf(m2, att4[2], t);
        t = fmaf(m3, att4[3], t);
        t += __shfl_xor(t, 1);
        t += __shfl_xor(t, 2);
        if (slot == 0 && (lane & 3) == 0)
          alpha[(size_t)e * 4 + head] = __expf(t) * dinv;
      }
    }
  }
}

// ---------------- GRU gates (elementwise) ----------------
__global__ void k_gates(const float* __restrict__ gbuf, const float* __restrict__ ghn,
                        const float* __restrict__ hs, float* __restrict__ outnh) {
  int i = blockIdx.x * 256 + threadIdx.x;
  if (i >= N_ * 64) return;
  int v = i >> 6, c = i & 63;
  float a = gbuf[(size_t)v * 192 + c];
  float b = gbuf[(size_t)v * 192 + 64 + c];
  float gn = gbuf[(size_t)v * 192 + 128 + c];
  float hn = ghn[i];
  float sv = hs[i];
  float r = 1.f / (1.f + __expf(-a));
  float z = 1.f / (1.f + __expf(-b));
  float n = tanhf(gn + r * hn);
  outnh[i] = (1.f - z) * n + z * sv;
}

// ---------------- Decoder layer 2 (N=7) ----------------
__global__ __launch_bounds__(256) void k_dec2(
    const float* __restrict__ d,
    const float* __restrict__ w2, const float* __restrict__ b2,
    float* __restrict__ out) {
  __shared__ float ws[64 * 7];
  __shared__ float bs[8];
  for (int i = threadIdx.x; i < 64 * 7; i += 256) ws[i] = w2[i];
  if (threadIdx.x < 7) bs[threadIdx.x] = b2[threadIdx.x];
  __syncthreads();
  int v = blockIdx.x * 256 + threadIdx.x;
  if (v >= N_) return;
  float o[7];
#pragma unroll
  for (int u = 0; u < 7; ++u) o[u] = bs[u];
  for (int k = 0; k < 64; k += 4) {
    float4 dv = *(const float4*)(d + (size_t)v * 64 + k);
#pragma unroll
    for (int t = 0; t < 4; ++t) {
      float x = fcomp(dv, t);
#pragma unroll
      for (int u = 0; u < 7; ++u) o[u] = fmaf(x, ws[(k + t) * 7 + u], o[u]);
    }
  }
#pragma unroll
  for (int u = 0; u < 7; ++u) out[(size_t)v * 7 + u] = o[u];
}

extern "C" void kernel_launch(void* const* d_in, const int* in_sizes, int n_in,
                              void* d_out, int out_size, void* d_ws, size_t ws_size,
                              hipStream_t stream) {
  const float* x      = (const float*)d_in[0];
  const int* ntype    = (const int*)d_in[1];
  const int* sid      = (const int*)d_in[2];
  const int* ei       = (const int*)d_in[3];
  const float* eattr  = (const float*)d_in[4];
  const float* hs     = (const float*)d_in[5];
  const float* temb   = (const float*)d_in[6];
  const float* semb   = (const float*)d_in[7];
  const float* enc_w1 = (const float*)d_in[8];
  const float* enc_b1 = (const float*)d_in[9];
  const float* enc_w2 = (const float*)d_in[10];
  const float* enc_b2 = (const float*)d_in[11];
  const float* g1_wl  = (const float*)d_in[12];
  const float* g1_bl  = (const float*)d_in[13];
  const float* g1_wr  = (const float*)d_in[14];
  const float* g1_br  = (const float*)d_in[15];
  const float* g1_we  = (const float*)d_in[16];
  const float* g1_att = (const float*)d_in[17];
  const float* g1_bias= (const float*)d_in[18];
  const float* g2_wl  = (const float*)d_in[19];
  const float* g2_bl  = (const float*)d_in[20];
  const float* g2_wr  = (const float*)d_in[21];
  const float* g2_br  = (const float*)d_in[22];
  const float* g2_we  = (const float*)d_in[23];
  const float* g2_att = (const float*)d_in[24];
  const float* g2_bias= (const float*)d_in[25];
  const float* gru_wih= (const float*)d_in[26];
  const float* gru_bih= (const float*)d_in[27];
  const float* gru_whh= (const float*)d_in[28];
  const float* gru_bhh= (const float*)d_in[29];
  const float* dec_w1 = (const float*)d_in[30];
  const float* dec_b1 = (const float*)d_in[31];
  const float* dec_w2 = (const float*)d_in[32];
  const float* dec_b2 = (const float*)d_in[33];

  float* ws = (float*)d_ws;
  float* hA = ws;               // N*64
  float* hB = hA + N_ * 64;     // N*64  (gbuf = hB spans hB|xl|xr at GRU time)
  float* xl = hB + N_ * 64;     // N*64
  float* xr = xl + N_ * 64;     // N*64
  float* U  = xr + N_ * 64;     // N*64: IN[N,24] (enc time) / ghn[N,64] (GRU time)
  int* deg  = (int*)(U + N_ * 64);   // N
  int* off  = deg + N_;              // N+1
  int* cur  = off + N_ + 1;          // N
  int* bsum = cur + N_;              // 64 (pad -> csr_es 8B aligned)
  int2* csr_es = (int2*)(bsum + 64); // E pairs

  float* IN   = U;    // N*24
  float* gbuf = hB;   // N*192 spans hB|xl|xr
  float* ghn  = U;    // N*64

  float* out0  = (float*)d_out;      // N*7
  float* outnh = out0 + N_ * 7;      // N*64
  float* outa1 = outnh + N_ * 64;    // E*4
  float* outa2 = outa1 + E_ * 4;     // E*4

  const int NB_SCAN = (N_ + 1023) / 1024;  // 49
  const int NB_NODE = (N_ + 255) / 256;    // 196
  const int NB_GEMM = (N_ + 127) / 128;    // 391

  hipMemsetAsync(deg, 0, N_ * sizeof(int), stream);
  k_hist<<<(E_ + 255) / 256, 256, 0, stream>>>(ei, deg);
  k_scan_blk<<<NB_SCAN, 1024, 0, stream>>>(deg, off, bsum);
  k_scan_top<<<1, 64, 0, stream>>>(bsum, NB_SCAN);
  k_scan_add<<<(N_ + 255) / 256, 256, 0, stream>>>(off, bsum, cur);
  k_scatter<<<(E_ + 255) / 256, 256, 0, stream>>>(ei, cur, csr_es);

  // Encoder: gather -> GEMM(K24, relu) -> GEMM(K64)
  k_gather<<<NB_NODE, 256, 0, stream>>>(x, ntype, sid, temb, semb, IN);
  k_gemm<24, true, false><<<NB_GEMM, 256, 0, stream>>>(IN, 24, 23, enc_w1, 64, enc_b1, hB, 64);
  k_gemm<64, false, false><<<NB_GEMM, 256, 0, stream>>>(hB, 64, 64, enc_w2, 64, enc_b2, hA, 64);
  // GAT layer 1: hA -> hB (relu)
  k_gemm<64, false, false><<<NB_GEMM, 256, 0, stream>>>(hA, 64, 64, g1_wl, 64, g1_bl, xl, 64);
  k_gemm<64, false, false><<<NB_GEMM, 256, 0, stream>>>(hA, 64, 64, g1_wr, 64, g1_br, xr, 64);
  k_fused<true><<<2048, 256, 0, stream>>>(off, csr_es, eattr, xl, xr,
                                          g1_we, g1_att, g1_bias, hB, outa1);
  // GAT layer 2: hB -> hA (no relu)
  k_gemm<64, false, false><<<NB_GEMM, 256, 0, stream>>>(hB, 64, 64, g2_wl, 64, g2_bl, xl, 64);
  k_gemm<64, false, false><<<NB_GEMM, 256, 0, stream>>>(hB, 64, 64, g2_wr, 64, g2_br, xr, 64);
  k_fused<false><<<2048, 256, 0, stream>>>(off, csr_es, eattr, xl, xr,
                                           g2_we, g2_att, g2_bias, hA, outa2);
  // GRU: gi chunks into gbuf (row stride 192), gh r/z accumulated, ghn separate
  k_gemm<64, false, false><<<NB_GEMM, 256, 0, stream>>>(hA, 64, 64, gru_wih, 192, gru_bih, gbuf, 192);
  k_gemm<64, false, false><<<NB_GEMM, 256, 0, stream>>>(hA, 64, 64, gru_wih + 64, 192, gru_bih + 64, gbuf + 64, 192);
  k_gemm<64, false, false><<<NB_GEMM, 256, 0, stream>>>(hA, 64, 64, gru_wih + 128, 192, gru_bih + 128, gbuf + 128, 192);
  k_gemm<64, false, true><<<NB_GEMM, 256, 0, stream>>>(hs, 64, 64, gru_whh, 192, gru_bhh, gbuf, 192);
  k_gemm<64, false, true><<<NB_GEMM, 256, 0, stream>>>(hs, 64, 64, gru_whh + 64, 192, gru_bhh + 64, gbuf + 64, 192);
  k_gemm<64, false, false><<<NB_GEMM, 256, 0, stream>>>(hs, 64, 64, gru_whh + 128, 192, gru_bhh + 128, ghn, 64);
  k_gates<<<(N_ * 64 + 255) / 256, 256, 0, stream>>>(gbuf, ghn, hs, outnh);
  // Decoder
  k_gemm<64, true, false><<<NB_GEMM, 256, 0, stream>>>(outnh, 64, 64, dec_w1, 64, dec_b1, xl, 64);
  k_dec2<<<NB_NODE, 256, 0, stream>>>(xl, dec_w2, dec_b2, out0);
}

// Round 7
// 551.254 us; speedup vs baseline: 3.7752x; 3.7752x over previous
//
#include <hip/hip_runtime.h>
#include <hip/hip_bf16.h>

static constexpr int N_ = 50000;
static constexpr int E_ = 800000;
static constexpr int CAP = 128;   // per-wave LDS edge cache (max degree fast-path)

// ---------------- CSR build ----------------
__global__ void k_hist(const int* __restrict__ ei, int* __restrict__ deg) {
  int e = blockIdx.x * blockDim.x + threadIdx.x;
  if (e < E_) atomicAdd(&deg[ei[E_ + e]], 1);
}

__global__ __launch_bounds__(1024) void k_scan_blk(const int* __restrict__ deg,
                                                   int* __restrict__ off,
                                                   int* __restrict__ bsum) {
  __shared__ int sm[1024];
  int t = threadIdx.x;
  int i = blockIdx.x * 1024 + t;
  int v = (i < N_) ? deg[i] : 0;
  sm[t] = v;
  __syncthreads();
  for (int s = 1; s < 1024; s <<= 1) {
    int u = (t >= s) ? sm[t - s] : 0;
    __syncthreads();
    sm[t] += u;
    __syncthreads();
  }
  if (i < N_) off[i] = sm[t] - v;
  if (t == 1023) bsum[blockIdx.x] = sm[t];
}

__global__ void k_scan_top(int* __restrict__ bsum, int nb) {
  int t = threadIdx.x;  // 64
  int v = (t < nb) ? bsum[t] : 0;
  int orig = v;
  for (int s = 1; s < 64; s <<= 1) {
    int u = __shfl_up(v, s);
    if (t >= s) v += u;
  }
  if (t < nb) bsum[t] = v - orig;
}

__global__ void k_scan_add(int* __restrict__ off, const int* __restrict__ bsum,
                           int* __restrict__ cur) {
  int i = blockIdx.x * blockDim.x + threadIdx.x;
  if (i < N_) {
    int o = off[i] + bsum[i >> 10];
    off[i] = o;
    cur[i] = o;
  }
  if (i == 0) off[N_] = E_;
}

__global__ void k_scatter(const int* __restrict__ ei, int* __restrict__ cursor,
                          int2* __restrict__ csr_es) {
  int e = blockIdx.x * blockDim.x + threadIdx.x;
  if (e < E_) {
    int s = ei[e];
    int d = ei[E_ + e];
    int p = atomicAdd(&cursor[d], 1);
    csr_es[p] = make_int2(e, s);
  }
}

// ---------------- Encoder input gather: IN[N,24] (col 23 = 0) ----------------
__global__ void k_gather(const float* __restrict__ x, const int* __restrict__ ntype,
                         const int* __restrict__ sid,
                         const float* __restrict__ temb, const float* __restrict__ semb,
                         float* __restrict__ IN) {
  int v = blockIdx.x * 256 + threadIdx.x;
  if (v >= N_) return;
  float in[24];
#pragma unroll
  for (int i = 0; i < 7; ++i) in[i] = x[v * 7 + i];
  int nt = ntype[v], sd = sid[v];
#pragma unroll
  for (int i = 0; i < 8; ++i) in[7 + i] = temb[nt * 8 + i];
#pragma unroll
  for (int i = 0; i < 8; ++i) in[15 + i] = semb[sd * 8 + i];
  in[23] = 0.f;
#pragma unroll
  for (int q = 0; q < 6; ++q)
    *(float4*)(IN + (size_t)v * 24 + q * 4) =
        make_float4(in[q * 4], in[q * 4 + 1], in[q * 4 + 2], in[q * 4 + 3]);
}

// ---------------- Tiled GEMM: C[M,64] = act(A[M,K] @ W[K,64] + b) ----------------
// 256 thr: col = tid&7 (8 output-quads), rowb = tid>>3 (32); nodes rowb+32*i.
// blockIdx.y selects a 64-column chunk of W/bias/C (for fused multi-gate GEMMs).
// kg-loop deliberately NOT unrolled (spill guard); At in [KQ][129] float4 layout
// -> conflict-free fragment reads, coalesced staging.
template <int KPAD, bool RELU, bool ACC>
__global__ __launch_bounds__(256, 3) void k_gemm(
    const float* __restrict__ A, int lda, int Kreal,
    const float* __restrict__ W, int ldw,
    const float* __restrict__ bias,
    float* __restrict__ C, int ldc) {
  constexpr int KQ = KPAD / 4;
  __shared__ float4 At4[KQ * 129];
  __shared__ float Wt[KPAD * 64];
  int tid = threadIdx.x;
  int nb = blockIdx.x * 128;
  int cb = blockIdx.y * 64;   // column chunk
  W += cb; bias += cb; C += cb;
  // stage W (zero rows k >= Kreal)
  for (int idx = tid; idx < KPAD * 16; idx += 256) {
    int k = idx >> 4, jq = idx & 15;
    float4 v = (k < Kreal) ? *(const float4*)(W + (size_t)k * ldw + jq * 4)
                           : make_float4(0.f, 0.f, 0.f, 0.f);
    *(float4*)(Wt + k * 64 + jq * 4) = v;
  }
  // stage A node-major (coalesced global reads; <=2-way LDS write conflicts)
  for (int idx = tid; idx < 128 * KQ; idx += 256) {
    int r = idx / KQ, kq = idx - r * KQ;
    int node = nb + r;
    float4 v = (node < N_) ? *(const float4*)(A + (size_t)node * lda + kq * 4)
                           : make_float4(0.f, 0.f, 0.f, 0.f);
    At4[kq * 129 + r] = v;
  }
  __syncthreads();
  int col = tid & 7, rowb = tid >> 3;
  int j0 = col * 8;
  float4 b0 = *(const float4*)(bias + j0);
  float4 b1 = *(const float4*)(bias + j0 + 4);
  float acc[4][8];
#pragma unroll
  for (int i = 0; i < 4; ++i) {
    acc[i][0] = b0.x; acc[i][1] = b0.y; acc[i][2] = b0.z; acc[i][3] = b0.w;
    acc[i][4] = b1.x; acc[i][5] = b1.y; acc[i][6] = b1.z; acc[i][7] = b1.w;
  }
#pragma unroll 1
  for (int kg = 0; kg < KQ; ++kg) {
    float4 a0 = At4[kg * 129 + rowb];
    float4 a1 = At4[kg * 129 + rowb + 32];
    float4 a2 = At4[kg * 129 + rowb + 64];
    float4 a3 = At4[kg * 129 + rowb + 96];
#pragma unroll
    for (int t = 0; t < 4; ++t) {
      float4 w0 = *(const float4*)(Wt + (kg * 4 + t) * 64 + j0);
      float4 w1 = *(const float4*)(Wt + (kg * 4 + t) * 64 + j0 + 4);
      float av0 = t == 0 ? a0.x : t == 1 ? a0.y : t == 2 ? a0.z : a0.w;
      float av1 = t == 0 ? a1.x : t == 1 ? a1.y : t == 2 ? a1.z : a1.w;
      float av2 = t == 0 ? a2.x : t == 1 ? a2.y : t == 2 ? a2.z : a2.w;
      float av3 = t == 0 ? a3.x : t == 1 ? a3.y : t == 2 ? a3.z : a3.w;
      acc[0][0] = fmaf(av0, w0.x, acc[0][0]); acc[0][1] = fmaf(av0, w0.y, acc[0][1]);
      acc[0][2] = fmaf(av0, w0.z, acc[0][2]); acc[0][3] = fmaf(av0, w0.w, acc[0][3]);
      acc[0][4] = fmaf(av0, w1.x, acc[0][4]); acc[0][5] = fmaf(av0, w1.y, acc[0][5]);
      acc[0][6] = fmaf(av0, w1.z, acc[0][6]); acc[0][7] = fmaf(av0, w1.w, acc[0][7]);
      acc[1][0] = fmaf(av1, w0.x, acc[1][0]); acc[1][1] = fmaf(av1, w0.y, acc[1][1]);
      acc[1][2] = fmaf(av1, w0.z, acc[1][2]); acc[1][3] = fmaf(av1, w0.w, acc[1][3]);
      acc[1][4] = fmaf(av1, w1.x, acc[1][4]); acc[1][5] = fmaf(av1, w1.y, acc[1][5]);
      acc[1][6] = fmaf(av1, w1.z, acc[1][6]); acc[1][7] = fmaf(av1, w1.w, acc[1][7]);
      acc[2][0] = fmaf(av2, w0.x, acc[2][0]); acc[2][1] = fmaf(av2, w0.y, acc[2][1]);
      acc[2][2] = fmaf(av2, w0.z, acc[2][2]); acc[2][3] = fmaf(av2, w0.w, acc[2][3]);
      acc[2][4] = fmaf(av2, w1.x, acc[2][4]); acc[2][5] = fmaf(av2, w1.y, acc[2][5]);
      acc[2][6] = fmaf(av2, w1.z, acc[2][6]); acc[2][7] = fmaf(av2, w1.w, acc[2][7]);
      acc[3][0] = fmaf(av3, w0.x, acc[3][0]); acc[3][1] = fmaf(av3, w0.y, acc[3][1]);
      acc[3][2] = fmaf(av3, w0.z, acc[3][2]); acc[3][3] = fmaf(av3, w0.w, acc[3][3]);
      acc[3][4] = fmaf(av3, w1.x, acc[3][4]); acc[3][5] = fmaf(av3, w1.y, acc[3][5]);
      acc[3][6] = fmaf(av3, w1.z, acc[3][6]); acc[3][7] = fmaf(av3, w1.w, acc[3][7]);
    }
  }
#pragma unroll
  for (int i = 0; i < 4; ++i) {
    int node = nb + rowb + 32 * i;
    if (node < N_) {
      float* cp = C + (size_t)node * ldc + j0;
      float o0 = acc[i][0], o1 = acc[i][1], o2 = acc[i][2], o3 = acc[i][3];
      float o4 = acc[i][4], o5 = acc[i][5], o6 = acc[i][6], o7 = acc[i][7];
      if (RELU) {
        o0 = fmaxf(o0, 0.f); o1 = fmaxf(o1, 0.f); o2 = fmaxf(o2, 0.f); o3 = fmaxf(o3, 0.f);
        o4 = fmaxf(o4, 0.f); o5 = fmaxf(o5, 0.f); o6 = fmaxf(o6, 0.f); o7 = fmaxf(o7, 0.f);
      }
      if (ACC) {
        float4 c0 = *(const float4*)cp;
        float4 c1 = *(const float4*)(cp + 4);
        o0 += c0.x; o1 += c0.y; o2 += c0.z; o3 += c0.w;
        o4 += c1.x; o5 += c1.y; o6 += c1.z; o7 += c1.w;
      }
      *(float4*)cp = make_float4(o0, o1, o2, o3);
      *(float4*)(cp + 4) = make_float4(o4, o5, o6, o7);
    }
  }
}

// ---------------- Fused GAT: 4 edges x 16 lanes per wave ----------------
template <bool RELU>
__global__ __launch_bounds__(256) void k_fused(
    const int* __restrict__ off, const int2* __restrict__ csr_es,
    const float* __restrict__ eattr,
    const float* __restrict__ xl, const float* __restrict__ xr,
    const float* __restrict__ we, const float* __restrict__ att,
    const float* __restrict__ bias,
    float* __restrict__ hout, float* __restrict__ alpha) {
  __shared__ float exbuf[4][CAP * 4];
  __shared__ int ebuf[4][CAP];
  int tid = threadIdx.x;
  int lane = tid & 63, wv = tid >> 6;
  int slot = lane >> 4;       // edge slot 0..3
  int q = lane & 15;          // channel quad: channels q*4 .. q*4+3
  int head = q >> 2;
  int sb = slot << 4;
  float wef[6][4], att4[4], b4[4];
#pragma unroll
  for (int i = 0; i < 6; ++i)
#pragma unroll
    for (int r = 0; r < 4; ++r) wef[i][r] = we[i * 64 + q * 4 + r];
#pragma unroll
  for (int r = 0; r < 4; ++r) { att4[r] = att[q * 4 + r]; b4[r] = bias[q * 4 + r]; }

  int wid = (blockIdx.x * blockDim.x + tid) >> 6;
  int nw = (gridDim.x * blockDim.x) >> 6;
  for (int v = wid; v < N_; v += nw) {
    int p0 = off[v], p1 = off[v + 1];
    int cnt = p1 - p0;
    float4 xr4 = *(const float4*)(xr + (size_t)v * 64 + q * 4);
    float num0 = 0.f, num1 = 0.f, num2 = 0.f, num3 = 0.f, den = 0.f;
    int p = p0 + slot;
    int2 es = (p < p1) ? csr_es[p] : make_int2(0, 0);
    for (int base = 0; base < cnt; base += 4) {
      bool valid = (p0 + base + slot) < p1;
      int e = es.x, s = es.y;
      int pn = p0 + base + 4 + slot;
      int2 esn = (pn < p1) ? csr_es[pn] : make_int2(0, 0);
      float ea = (valid && q < 6) ? eattr[(size_t)e * 6 + q] : 0.f;
      float4 xls = valid ? *(const float4*)(xl + (size_t)s * 64 + q * 4)
                         : make_float4(0.f, 0.f, 0.f, 0.f);
      float m0 = xls.x + xr4.x, m1 = xls.y + xr4.y, m2 = xls.z + xr4.z, m3 = xls.w + xr4.w;
#pragma unroll
      for (int i = 0; i < 6; ++i) {
        float eai = __shfl(ea, sb + i);
        m0 = fmaf(eai, wef[i][0], m0);
        m1 = fmaf(eai, wef[i][1], m1);
        m2 = fmaf(eai, wef[i][2], m2);
        m3 = fmaf(eai, wef[i][3], m3);
      }
      m0 = (m0 > 0.f) ? m0 : 0.2f * m0;
      m1 = (m1 > 0.f) ? m1 : 0.2f * m1;
      m2 = (m2 > 0.f) ? m2 : 0.2f * m2;
      m3 = (m3 > 0.f) ? m3 : 0.2f * m3;
      float t = m0 * att4[0];
      t = fmaf(m1, att4[1], t);
      t = fmaf(m2, att4[2], t);
      t = fmaf(m3, att4[3], t);
      t += __shfl_xor(t, 1);
      t += __shfl_xor(t, 2);
      float ex = valid ? __expf(t) : 0.f;
      den += ex;
      num0 = fmaf(xls.x, ex, num0);
      num1 = fmaf(xls.y, ex, num1);
      num2 = fmaf(xls.z, ex, num2);
      num3 = fmaf(xls.w, ex, num3);
      int idx = base + slot;
      if (valid && idx < CAP) {
        if ((lane & 3) == 0) exbuf[wv][idx * 4 + head] = ex;
        if (q == 0) ebuf[wv][idx] = e;
      }
      es = esn;
    }
    num0 += __shfl_xor(num0, 16); num0 += __shfl_xor(num0, 32);
    num1 += __shfl_xor(num1, 16); num1 += __shfl_xor(num1, 32);
    num2 += __shfl_xor(num2, 16); num2 += __shfl_xor(num2, 32);
    num3 += __shfl_xor(num3, 16); num3 += __shfl_xor(num3, 32);
    den  += __shfl_xor(den, 16);  den  += __shfl_xor(den, 32);
    float dinv = 1.f / (den + 1e-16f);
    float o0 = fmaf(num0, dinv, b4[0]);
    float o1 = fmaf(num1, dinv, b4[1]);
    float o2 = fmaf(num2, dinv, b4[2]);
    float o3 = fmaf(num3, dinv, b4[3]);
    if (RELU) {
      o0 = fmaxf(o0, 0.f); o1 = fmaxf(o1, 0.f); o2 = fmaxf(o2, 0.f); o3 = fmaxf(o3, 0.f);
    }
    if (slot == 0)
      *(float4*)(hout + (size_t)v * 64 + q * 4) = make_float4(o0, o1, o2, o3);
    float dh = __shfl(dinv, (lane & 3) << 2);
    if (cnt <= CAP) {
      for (int base2 = 0; base2 < cnt; base2 += 16) {
        int idx = base2 + (lane >> 2);
        if (idx < cnt) {
          float exv = exbuf[wv][idx * 4 + (lane & 3)];
          int e = ebuf[wv][idx];
          alpha[(size_t)e * 4 + (lane & 3)] = exv * dh;
        }
      }
    } else {
      for (int pp = p0; pp < p1; ++pp) {
        int2 es2 = csr_es[pp];
        int e = es2.x, s = es2.y;
        float ea = (q < 6) ? eattr[(size_t)e * 6 + q] : 0.f;
        float4 xls = *(const float4*)(xl + (size_t)s * 64 + q * 4);
        float m0 = xls.x + xr4.x, m1 = xls.y + xr4.y, m2 = xls.z + xr4.z, m3 = xls.w + xr4.w;
#pragma unroll
        for (int i = 0; i < 6; ++i) {
          float eai = __shfl(ea, i);
          m0 = fmaf(eai, wef[i][0], m0);
          m1 = fmaf(eai, wef[i][1], m1);
          m2 = fmaf(eai, wef[i][2], m2);
          m3 = fmaf(eai, wef[i][3], m3);
        }
        m0 = (m0 > 0.f) ? m0 : 0.2f * m0;
        m1 = (m1 > 0.f) ? m1 : 0.2f * m1;
        m2 = (m2 > 0.f) ? m2 : 0.2f * m2;
        m3 = (m3 > 0.f) ? m3 : 0.2f * m3;
        float t = m0 * att4[0];
        t = fmaf(m1, att4[1], t);
        t = fmaf(m2, att4[2], t);
        t = fmaf(m3, att4[3], t);
        t += __shfl_xor(t, 1);
        t += __shfl_xor(t, 2);
        if (slot == 0 && (lane & 3) == 0)
          alpha[(size_t)e * 4 + head] = __expf(t) * dinv;
      }
    }
  }
}

// ---------------- GRU gates (elementwise) ----------------
__global__ void k_gates(const float* __restrict__ gbuf, const float* __restrict__ ghn,
                        const float* __restrict__ hs, float* __restrict__ outnh) {
  int i = blockIdx.x * 256 + threadIdx.x;
  if (i >= N_ * 64) return;
  int v = i >> 6, c = i & 63;
  float a = gbuf[(size_t)v * 192 + c];
  float b = gbuf[(size_t)v * 192 + 64 + c];
  float gn = gbuf[(size_t)v * 192 + 128 + c];
  float hn = ghn[i];
  float sv = hs[i];
  float r = 1.f / (1.f + __expf(-a));
  float z = 1.f / (1.f + __expf(-b));
  float n = tanhf(gn + r * hn);
  outnh[i] = (1.f - z) * n + z * sv;
}

// ---------------- Decoder layer 2 (N=7) ----------------
__global__ __launch_bounds__(256) void k_dec2(
    const float* __restrict__ d,
    const float* __restrict__ w2, const float* __restrict__ b2,
    float* __restrict__ out) {
  __shared__ float ws[64 * 7];
  __shared__ float bs[8];
  for (int i = threadIdx.x; i < 64 * 7; i += 256) ws[i] = w2[i];
  if (threadIdx.x < 7) bs[threadIdx.x] = b2[threadIdx.x];
  __syncthreads();
  int v = blockIdx.x * 256 + threadIdx.x;
  if (v >= N_) return;
  float o[7];
#pragma unroll
  for (int u = 0; u < 7; ++u) o[u] = bs[u];
  for (int k = 0; k < 64; k += 4) {
    float4 dv = *(const float4*)(d + (size_t)v * 64 + k);
#pragma unroll
    for (int t = 0; t < 4; ++t) {
      float x = t == 0 ? dv.x : t == 1 ? dv.y : t == 2 ? dv.z : dv.w;
#pragma unroll
      for (int u = 0; u < 7; ++u) o[u] = fmaf(x, ws[(k + t) * 7 + u], o[u]);
    }
  }
#pragma unroll
  for (int u = 0; u < 7; ++u) out[(size_t)v * 7 + u] = o[u];
}

extern "C" void kernel_launch(void* const* d_in, const int* in_sizes, int n_in,
                              void* d_out, int out_size, void* d_ws, size_t ws_size,
                              hipStream_t stream) {
  const float* x      = (const float*)d_in[0];
  const int* ntype    = (const int*)d_in[1];
  const int* sid      = (const int*)d_in[2];
  const int* ei       = (const int*)d_in[3];
  const float* eattr  = (const float*)d_in[4];
  const float* hs     = (const float*)d_in[5];
  const float* temb   = (const float*)d_in[6];
  const float* semb   = (const float*)d_in[7];
  const float* enc_w1 = (const float*)d_in[8];
  const float* enc_b1 = (const float*)d_in[9];
  const float* enc_w2 = (const float*)d_in[10];
  const float* enc_b2 = (const float*)d_in[11];
  const float* g1_wl  = (const float*)d_in[12];
  const float* g1_bl  = (const float*)d_in[13];
  const float* g1_wr  = (const float*)d_in[14];
  const float* g1_br  = (const float*)d_in[15];
  const float* g1_we  = (const float*)d_in[16];
  const float* g1_att = (const float*)d_in[17];
  const float* g1_bias= (const float*)d_in[18];
  const float* g2_wl  = (const float*)d_in[19];
  const float* g2_bl  = (const float*)d_in[20];
  const float* g2_wr  = (const float*)d_in[21];
  const float* g2_br  = (const float*)d_in[22];
  const float* g2_we  = (const float*)d_in[23];
  const float* g2_att = (const float*)d_in[24];
  const float* g2_bias= (const float*)d_in[25];
  const float* gru_wih= (const float*)d_in[26];
  const float* gru_bih= (const float*)d_in[27];
  const float* gru_whh= (const float*)d_in[28];
  const float* gru_bhh= (const float*)d_in[29];
  const float* dec_w1 = (const float*)d_in[30];
  const float* dec_b1 = (const float*)d_in[31];
  const float* dec_w2 = (const float*)d_in[32];
  const float* dec_b2 = (const float*)d_in[33];

  float* ws = (float*)d_ws;
  float* hA = ws;               // N*64
  float* hB = hA + N_ * 64;     // N*64  (gbuf = hB spans hB|xl|xr at GRU time)
  float* xl = hB + N_ * 64;     // N*64
  float* xr = xl + N_ * 64;     // N*64
  float* U  = xr + N_ * 64;     // N*64: IN[N,24] (enc time) / ghn[N,64] (GRU time)
  int* deg  = (int*)(U + N_ * 64);   // N
  int* off  = deg + N_;              // N+1
  int* cur  = off + N_ + 1;          // N
  int* bsum = cur + N_;              // 64 (pad -> csr_es 8B aligned)
  int2* csr_es = (int2*)(bsum + 64); // E pairs

  float* IN   = U;    // N*24
  float* gbuf = hB;   // N*192 spans hB|xl|xr
  float* ghn  = U;    // N*64

  float* out0  = (float*)d_out;      // N*7
  float* outnh = out0 + N_ * 7;      // N*64
  float* outa1 = outnh + N_ * 64;    // E*4
  float* outa2 = outa1 + E_ * 4;     // E*4

  const int NB_SCAN = (N_ + 1023) / 1024;  // 49
  const int NB_NODE = (N_ + 255) / 256;    // 196
  const int NB_GEMM = (N_ + 127) / 128;    // 391

  hipMemsetAsync(deg, 0, N_ * sizeof(int), stream);
  k_hist<<<(E_ + 255) / 256, 256, 0, stream>>>(ei, deg);
  k_scan_blk<<<NB_SCAN, 1024, 0, stream>>>(deg, off, bsum);
  k_scan_top<<<1, 64, 0, stream>>>(bsum, NB_SCAN);
  k_scan_add<<<(N_ + 255) / 256, 256, 0, stream>>>(off, bsum, cur);
  k_scatter<<<(E_ + 255) / 256, 256, 0, stream>>>(ei, cur, csr_es);

  // Encoder: gather -> GEMM(K24, relu) -> GEMM(K64)
  k_gather<<<NB_NODE, 256, 0, stream>>>(x, ntype, sid, temb, semb, IN);
  k_gemm<24, true, false><<<NB_GEMM, 256, 0, stream>>>(IN, 24, 23, enc_w1, 64, enc_b1, hB, 64);
  k_gemm<64, false, false><<<NB_GEMM, 256, 0, stream>>>(hB, 64, 64, enc_w2, 64, enc_b2, hA, 64);
  // GAT layer 1: hA -> hB (relu)
  k_gemm<64, false, false><<<NB_GEMM, 256, 0, stream>>>(hA, 64, 64, g1_wl, 64, g1_bl, xl, 64);
  k_gemm<64, false, false><<<NB_GEMM, 256, 0, stream>>>(hA, 64, 64, g1_wr, 64, g1_br, xr, 64);
  k_fused<true><<<2048, 256, 0, stream>>>(off, csr_es, eattr, xl, xr,
                                          g1_we, g1_att, g1_bias, hB, outa1);
  // GAT layer 2: hB -> hA (no relu)
  k_gemm<64, false, false><<<NB_GEMM, 256, 0, stream>>>(hB, 64, 64, g2_wl, 64, g2_bl, xl, 64);
  k_gemm<64, false, false><<<NB_GEMM, 256, 0, stream>>>(hB, 64, 64, g2_wr, 64, g2_br, xr, 64);
  k_fused<false><<<2048, 256, 0, stream>>>(off, csr_es, eattr, xl, xr,
                                           g2_we, g2_att, g2_bias, hA, outa2);
  // GRU: gi (3 column-chunks in one dispatch), gh r/z accumulated (2 chunks), ghn separate
  k_gemm<64, false, false><<<dim3(NB_GEMM, 3), 256, 0, stream>>>(hA, 64, 64, gru_wih, 192, gru_bih, gbuf, 192);
  k_gemm<64, false, true><<<dim3(NB_GEMM, 2), 256, 0, stream>>>(hs, 64, 64, gru_whh, 192, gru_bhh, gbuf, 192);
  k_gemm<64, false, false><<<NB_GEMM, 256, 0, stream>>>(hs, 64, 64, gru_whh + 128, 192, gru_bhh + 128, ghn, 64);
  k_gates<<<(N_ * 64 + 255) / 256, 256, 0, stream>>>(gbuf, ghn, hs, outnh);
  // Decoder
  k_gemm<64, true, false><<<NB_GEMM, 256, 0, stream>>>(outnh, 64, 64, dec_w1, 64, dec_b1, xl, 64);
  k_dec2<<<NB_NODE, 256, 0, stream>>>(xl, dec_w2, dec_b2, out0);
}

// Round 8
// 538.747 us; speedup vs baseline: 3.8629x; 1.0232x over previous
//
#include <hip/hip_runtime.h>
#include <hip/hip_bf16.h>

static constexpr int N_ = 50000;
static constexpr int E_ = 800000;
static constexpr int CAP = 128;   // per-wave LDS edge cache (max degree fast-path)

// ================= shared GEMM building blocks (128 nodes x 64 cols tile) =================
// 256 thr: col=tid&7 (8 output quads), rowb=tid>>3 (32 rows); nodes rowb+32*i.
// At4 pitch 129 float4 -> conflict-free fragment reads. kg-loop NOT unrolled (spill guard).

#define GEMM_FMA_BLOCK(AV, W0, W1, ROW)                                              \
      acc[ROW][0]=fmaf(AV,W0.x,acc[ROW][0]); acc[ROW][1]=fmaf(AV,W0.y,acc[ROW][1]);  \
      acc[ROW][2]=fmaf(AV,W0.z,acc[ROW][2]); acc[ROW][3]=fmaf(AV,W0.w,acc[ROW][3]);  \
      acc[ROW][4]=fmaf(AV,W1.x,acc[ROW][4]); acc[ROW][5]=fmaf(AV,W1.y,acc[ROW][5]);  \
      acc[ROW][6]=fmaf(AV,W1.z,acc[ROW][6]); acc[ROW][7]=fmaf(AV,W1.w,acc[ROW][7]);

#define GEMM_KLOOP(KQc)                                                              \
  _Pragma("unroll 1")                                                                \
  for (int kg = 0; kg < (KQc); ++kg) {                                               \
    float4 a0 = At4[kg * 129 + rowb];                                                \
    float4 a1 = At4[kg * 129 + rowb + 32];                                           \
    float4 a2 = At4[kg * 129 + rowb + 64];                                           \
    float4 a3 = At4[kg * 129 + rowb + 96];                                           \
    _Pragma("unroll")                                                                \
    for (int t = 0; t < 4; ++t) {                                                    \
      float4 w0 = *(const float4*)(Wt + (kg * 4 + t) * 64 + j0);                     \
      float4 w1 = *(const float4*)(Wt + (kg * 4 + t) * 64 + j0 + 4);                 \
      float av0 = t==0?a0.x:t==1?a0.y:t==2?a0.z:a0.w;                                \
      float av1 = t==0?a1.x:t==1?a1.y:t==2?a1.z:a1.w;                                \
      float av2 = t==0?a2.x:t==1?a2.y:t==2?a2.z:a2.w;                                \
      float av3 = t==0?a3.x:t==1?a3.y:t==2?a3.z:a3.w;                                \
      GEMM_FMA_BLOCK(av0, w0, w1, 0)                                                 \
      GEMM_FMA_BLOCK(av1, w0, w1, 1)                                                 \
      GEMM_FMA_BLOCK(av2, w0, w1, 2)                                                 \
      GEMM_FMA_BLOCK(av3, w0, w1, 3)                                                 \
    }                                                                                \
  }

#define ACC_INIT(BPTR)                                                               \
  {                                                                                  \
    float4 b0v = *(const float4*)((BPTR) + j0);                                      \
    float4 b1v = *(const float4*)((BPTR) + j0 + 4);                                  \
    _Pragma("unroll")                                                                \
    for (int i = 0; i < 4; ++i) {                                                    \
      acc[i][0]=b0v.x; acc[i][1]=b0v.y; acc[i][2]=b0v.z; acc[i][3]=b0v.w;            \
      acc[i][4]=b1v.x; acc[i][5]=b1v.y; acc[i][6]=b1v.z; acc[i][7]=b1v.w;            \
    }                                                                                \
  }

#define STAGE_W(WPTR, LDW, KPADc, KREAL)                                             \
  for (int idx = tid; idx < (KPADc) * 16; idx += 256) {                              \
    int k = idx >> 4, jq = idx & 15;                                                 \
    float4 v = (k < (KREAL)) ? *(const float4*)((WPTR) + (size_t)k * (LDW) + jq * 4) \
                             : make_float4(0.f, 0.f, 0.f, 0.f);                      \
    *(float4*)(Wt + k * 64 + jq * 4) = v;                                            \
  }

#define STAGE_A(APTR, LDA, KQc)                                                      \
  for (int idx = tid; idx < 128 * (KQc); idx += 256) {                               \
    int r = idx / (KQc), kq = idx - r * (KQc);                                       \
    int node = nb + r;                                                               \
    float4 v = (node < N_) ? *(const float4*)((APTR) + (size_t)node * (LDA) + kq * 4)\
                           : make_float4(0.f, 0.f, 0.f, 0.f);                        \
    At4[kq * 129 + r] = v;                                                           \
  }

#define STORE_C(CPTR, LDC, RELUc, ACCc)                                              \
  _Pragma("unroll")                                                                  \
  for (int i = 0; i < 4; ++i) {                                                      \
    int node = nb + rowb + 32 * i;                                                   \
    if (node < N_) {                                                                 \
      float* cp = (CPTR) + (size_t)node * (LDC) + j0;                                \
      float o0=acc[i][0],o1=acc[i][1],o2=acc[i][2],o3=acc[i][3];                     \
      float o4=acc[i][4],o5=acc[i][5],o6=acc[i][6],o7=acc[i][7];                     \
      if (RELUc) { o0=fmaxf(o0,0.f);o1=fmaxf(o1,0.f);o2=fmaxf(o2,0.f);o3=fmaxf(o3,0.f); \
                   o4=fmaxf(o4,0.f);o5=fmaxf(o5,0.f);o6=fmaxf(o6,0.f);o7=fmaxf(o7,0.f); } \
      if (ACCc) { float4 c0=*(const float4*)cp; float4 c1=*(const float4*)(cp+4);    \
                  o0+=c0.x;o1+=c0.y;o2+=c0.z;o3+=c0.w;o4+=c1.x;o5+=c1.y;o6+=c1.z;o7+=c1.w; } \
      *(float4*)cp = make_float4(o0,o1,o2,o3);                                       \
      *(float4*)(cp+4) = make_float4(o4,o5,o6,o7);                                   \
    }                                                                                \
  }

// ---------------- CSR build ----------------
__global__ void k_hist(const int* __restrict__ ei, int* __restrict__ deg) {
  int e = blockIdx.x * blockDim.x + threadIdx.x;
  if (e < E_) atomicAdd(&deg[ei[E_ + e]], 1);
}

__global__ __launch_bounds__(1024) void k_scan_blk(const int* __restrict__ deg,
                                                   int* __restrict__ off,
                                                   int* __restrict__ bsum) {
  __shared__ int sm[1024];
  int t = threadIdx.x;
  int i = blockIdx.x * 1024 + t;
  int v = (i < N_) ? deg[i] : 0;
  sm[t] = v;
  __syncthreads();
  for (int s = 1; s < 1024; s <<= 1) {
    int u = (t >= s) ? sm[t - s] : 0;
    __syncthreads();
    sm[t] += u;
    __syncthreads();
  }
  if (i < N_) off[i] = sm[t] - v;
  if (t == 1023) bsum[blockIdx.x] = sm[t];
}

__global__ void k_scan_top(int* __restrict__ bsum, int nb) {
  int t = threadIdx.x;  // 64
  int v = (t < nb) ? bsum[t] : 0;
  int orig = v;
  for (int s = 1; s < 64; s <<= 1) {
    int u = __shfl_up(v, s);
    if (t >= s) v += u;
  }
  if (t < nb) bsum[t] = v - orig;
}

__global__ void k_scan_add(int* __restrict__ off, const int* __restrict__ bsum,
                           int* __restrict__ cur) {
  int i = blockIdx.x * blockDim.x + threadIdx.x;
  if (i < N_) {
    int o = off[i] + bsum[i >> 10];
    off[i] = o;
    cur[i] = o;
  }
  if (i == 0) off[N_] = E_;
}

__global__ void k_scatter(const int* __restrict__ ei, int* __restrict__ cursor,
                          int2* __restrict__ csr_es) {
  int e = blockIdx.x * blockDim.x + threadIdx.x;
  if (e < E_) {
    int s = ei[e];
    int d = ei[E_ + e];
    int p = atomicAdd(&cursor[d], 1);
    csr_es[p] = make_int2(e, s);
  }
}

// ---------------- Encoder layer 1: fused gather + GEMM (K=24, relu) ----------------
__device__ __forceinline__ float encval(int c, int node, int nt, int sd,
                                        const float* __restrict__ x,
                                        const float* __restrict__ temb,
                                        const float* __restrict__ semb) {
  if (c < 7) return x[node * 7 + c];
  if (c < 15) return temb[nt * 8 + c - 7];
  if (c < 23) return semb[sd * 8 + c - 15];
  return 0.f;
}

__global__ __launch_bounds__(256, 3) void k_gemm_enc(
    const float* __restrict__ x, const int* __restrict__ ntype, const int* __restrict__ sid,
    const float* __restrict__ temb, const float* __restrict__ semb,
    const float* __restrict__ w1, const float* __restrict__ b1,
    float* __restrict__ hout) {
  __shared__ float4 At4[6 * 129];
  __shared__ float Wt[24 * 64];
  int tid = threadIdx.x;
  int nb = blockIdx.x * 128;
  for (int idx = tid; idx < 128 * 6; idx += 256) {
    int r = idx / 6, kq = idx - r * 6;
    int node = nb + r;
    float v0 = 0.f, v1 = 0.f, v2 = 0.f, v3 = 0.f;
    if (node < N_) {
      int nt = ntype[node], sd = sid[node];
      int c = kq * 4;
      v0 = encval(c, node, nt, sd, x, temb, semb);
      v1 = encval(c + 1, node, nt, sd, x, temb, semb);
      v2 = encval(c + 2, node, nt, sd, x, temb, semb);
      v3 = encval(c + 3, node, nt, sd, x, temb, semb);
    }
    At4[kq * 129 + r] = make_float4(v0, v1, v2, v3);
  }
  STAGE_W(w1, 64, 24, 23)
  __syncthreads();
  int col = tid & 7, rowb = tid >> 3;
  int j0 = col * 8;
  float acc[4][8];
  ACC_INIT(b1)
  GEMM_KLOOP(6)
  STORE_C(hout, 64, true, false)
}

// ---------------- Plain GEMM K=64 (encoder layer 2) ----------------
__global__ __launch_bounds__(256, 3) void k_gemm64(
    const float* __restrict__ A, const float* __restrict__ W,
    const float* __restrict__ bias, float* __restrict__ C) {
  __shared__ float4 At4[16 * 129];
  __shared__ float Wt[64 * 64];
  int tid = threadIdx.x;
  int nb = blockIdx.x * 128;
  STAGE_A(A, 64, 16)
  STAGE_W(W, 64, 64, 64)
  __syncthreads();
  int col = tid & 7, rowb = tid >> 3;
  int j0 = col * 8;
  float acc[4][8];
  ACC_INIT(bias)
  GEMM_KLOOP(16)
  STORE_C(C, 64, false, false)
}

// ---------------- Dual GEMM: xl = A@Wl+bl, xr = A@Wr+br (A staged once) ----------------
__global__ __launch_bounds__(256, 3) void k_gemm2(
    const float* __restrict__ A,
    const float* __restrict__ Wl, const float* __restrict__ bl,
    const float* __restrict__ Wr, const float* __restrict__ br,
    float* __restrict__ Cl, float* __restrict__ Cr) {
  __shared__ float4 At4[16 * 129];
  __shared__ float Wt[64 * 64];
  int tid = threadIdx.x;
  int nb = blockIdx.x * 128;
  STAGE_A(A, 64, 16)
  STAGE_W(Wl, 64, 64, 64)
  __syncthreads();
  int col = tid & 7, rowb = tid >> 3;
  int j0 = col * 8;
  float acc[4][8];
  ACC_INIT(bl)
  GEMM_KLOOP(16)
  STORE_C(Cl, 64, false, false)
  __syncthreads();
  STAGE_W(Wr, 64, 64, 64)
  __syncthreads();
  ACC_INIT(br)
  GEMM_KLOOP(16)
  STORE_C(Cr, 64, false, false)
}

// ---------------- GRU input-half: gbuf[:,0:192] = hA @ wih + bih (3 chunks, A once) ----
__global__ __launch_bounds__(256, 3) void k_gru_ih(
    const float* __restrict__ A,
    const float* __restrict__ wih, const float* __restrict__ bih,
    float* __restrict__ gbuf) {
  __shared__ float4 At4[16 * 129];
  __shared__ float Wt[64 * 64];
  int tid = threadIdx.x;
  int nb = blockIdx.x * 128;
  int col = tid & 7, rowb = tid >> 3;
  int j0 = col * 8;
  STAGE_A(A, 64, 16)
  for (int ch = 0; ch < 3; ++ch) {
    __syncthreads();
    STAGE_W(wih + ch * 64, 192, 64, 64)
    __syncthreads();
    float acc[4][8];
    ACC_INIT(bih + ch * 64)
    GEMM_KLOOP(16)
    STORE_C(gbuf + ch * 64, 192, false, false)
  }
}

// ---------------- GRU hidden-half + fused gates ----------------
// chunks 0,1: gbuf[:,0/64] += hs @ whh_rz + bhh_rz ; chunk 2: hn kept in regs; epilogue.
__global__ __launch_bounds__(256, 3) void k_gru_hh(
    const float* __restrict__ hs,
    const float* __restrict__ whh, const float* __restrict__ bhh,
    float* __restrict__ gbuf, float* __restrict__ outnh) {
  __shared__ float4 At4[16 * 129];
  __shared__ float Wt[64 * 64];
  int tid = threadIdx.x;
  int nb = blockIdx.x * 128;
  int col = tid & 7, rowb = tid >> 3;
  int j0 = col * 8;
  STAGE_A(hs, 64, 16)
  float acc[4][8];
  for (int ch = 0; ch < 3; ++ch) {
    __syncthreads();
    STAGE_W(whh + ch * 64, 192, 64, 64)
    __syncthreads();
    ACC_INIT(bhh + ch * 64)
    GEMM_KLOOP(16)
    if (ch < 2) { STORE_C(gbuf + ch * 64, 192, false, true) }
  }
  // epilogue: acc = hn for nodes rowb+32i, cols j0..j0+7
#define GATE1(RU, ZU, NU, SU, AU, OUT)                                   \
  { float rr = 1.f / (1.f + __expf(-(RU)));                              \
    float zz = 1.f / (1.f + __expf(-(ZU)));                              \
    float nn = tanhf((NU) + rr * (AU));                                  \
    OUT = (1.f - zz) * nn + zz * (SU); }
#pragma unroll
  for (int i = 0; i < 4; ++i) {
    int node = nb + rowb + 32 * i;
    if (node < N_) {
      const float* gp = gbuf + (size_t)node * 192;
      float4 r0 = *(const float4*)(gp + j0);
      float4 r1 = *(const float4*)(gp + j0 + 4);
      float4 z0 = *(const float4*)(gp + 64 + j0);
      float4 z1 = *(const float4*)(gp + 64 + j0 + 4);
      float4 n0 = *(const float4*)(gp + 128 + j0);
      float4 n1 = *(const float4*)(gp + 128 + j0 + 4);
      float4 s0 = *(const float4*)(hs + (size_t)node * 64 + j0);
      float4 s1 = *(const float4*)(hs + (size_t)node * 64 + j0 + 4);
      float q0, q1, q2, q3, q4, q5, q6, q7;
      GATE1(r0.x, z0.x, n0.x, s0.x, acc[i][0], q0)
      GATE1(r0.y, z0.y, n0.y, s0.y, acc[i][1], q1)
      GATE1(r0.z, z0.z, n0.z, s0.z, acc[i][2], q2)
      GATE1(r0.w, z0.w, n0.w, s0.w, acc[i][3], q3)
      GATE1(r1.x, z1.x, n1.x, s1.x, acc[i][4], q4)
      GATE1(r1.y, z1.y, n1.y, s1.y, acc[i][5], q5)
      GATE1(r1.z, z1.z, n1.z, s1.z, acc[i][6], q6)
      GATE1(r1.w, z1.w, n1.w, s1.w, acc[i][7], q7)
      float* op = outnh + (size_t)node * 64 + j0;
      *(float4*)op = make_float4(q0, q1, q2, q3);
      *(float4*)(op + 4) = make_float4(q4, q5, q6, q7);
    }
  }
#undef GATE1
}

// ---------------- Decoder: GEMM(relu) + layer-2 epilogue through LDS ----------------
__global__ __launch_bounds__(256, 3) void k_dec(
    const float* __restrict__ A,
    const float* __restrict__ w1, const float* __restrict__ b1,
    const float* __restrict__ w2, const float* __restrict__ b2,
    float* __restrict__ out) {
  __shared__ __align__(16) float pool[8320];   // At4 (33,024B) then dtile (33,280B)
  __shared__ float Wt[64 * 64];
  float4* At4 = (float4*)pool;
  float* dtile = pool;                          // aliased; separated by barriers
  int tid = threadIdx.x;
  int nb = blockIdx.x * 128;
  STAGE_A(A, 64, 16)
  STAGE_W(w1, 64, 64, 64)
  __syncthreads();
  int col = tid & 7, rowb = tid >> 3;
  int j0 = col * 8;
  float acc[4][8];
  ACC_INIT(b1)
  GEMM_KLOOP(16)
  __syncthreads();   // everyone done reading At4 before aliasing as dtile
#pragma unroll
  for (int i = 0; i < 4; ++i) {
    int rl = rowb + 32 * i;
#pragma unroll
    for (int u = 0; u < 8; ++u) dtile[rl * 65 + j0 + u] = fmaxf(acc[i][u], 0.f);
  }
  __syncthreads();
  if (tid < 128) {
    int node = nb + tid;
    if (node < N_) {
      float o0 = b2[0], o1 = b2[1], o2 = b2[2], o3 = b2[3], o4 = b2[4], o5 = b2[5], o6 = b2[6];
#pragma unroll 1
      for (int k = 0; k < 64; ++k) {
        float xv = dtile[tid * 65 + k];
        o0 = fmaf(xv, w2[k * 7 + 0], o0);
        o1 = fmaf(xv, w2[k * 7 + 1], o1);
        o2 = fmaf(xv, w2[k * 7 + 2], o2);
        o3 = fmaf(xv, w2[k * 7 + 3], o3);
        o4 = fmaf(xv, w2[k * 7 + 4], o4);
        o5 = fmaf(xv, w2[k * 7 + 5], o5);
        o6 = fmaf(xv, w2[k * 7 + 6], o6);
      }
      float* op = out + (size_t)node * 7;
      op[0] = o0; op[1] = o1; op[2] = o2; op[3] = o3; op[4] = o4; op[5] = o5; op[6] = o6;
    }
  }
}

// ---------------- Fused GAT: 4 edges x 16 lanes per wave ----------------
template <bool RELU>
__global__ __launch_bounds__(256) void k_fused(
    const int* __restrict__ off, const int2* __restrict__ csr_es,
    const float* __restrict__ eattr,
    const float* __restrict__ xl, const float* __restrict__ xr,
    const float* __restrict__ we, const float* __restrict__ att,
    const float* __restrict__ bias,
    float* __restrict__ hout, float* __restrict__ alpha) {
  __shared__ float exbuf[4][CAP * 4];
  __shared__ int ebuf[4][CAP];
  int tid = threadIdx.x;
  int lane = tid & 63, wv = tid >> 6;
  int slot = lane >> 4;       // edge slot 0..3
  int q = lane & 15;          // channel quad: channels q*4 .. q*4+3
  int head = q >> 2;
  int sb = slot << 4;
  float wef[6][4], att4[4], b4[4];
#pragma unroll
  for (int i = 0; i < 6; ++i)
#pragma unroll
    for (int r = 0; r < 4; ++r) wef[i][r] = we[i * 64 + q * 4 + r];
#pragma unroll
  for (int r = 0; r < 4; ++r) { att4[r] = att[q * 4 + r]; b4[r] = bias[q * 4 + r]; }

  int wid = (blockIdx.x * blockDim.x + tid) >> 6;
  int nw = (gridDim.x * blockDim.x) >> 6;
  for (int v = wid; v < N_; v += nw) {
    int p0 = off[v], p1 = off[v + 1];
    int cnt = p1 - p0;
    float4 xr4 = *(const float4*)(xr + (size_t)v * 64 + q * 4);
    float num0 = 0.f, num1 = 0.f, num2 = 0.f, num3 = 0.f, den = 0.f;
    int p = p0 + slot;
    int2 es = (p < p1) ? csr_es[p] : make_int2(0, 0);
    for (int base = 0; base < cnt; base += 4) {
      bool valid = (p0 + base + slot) < p1;
      int e = es.x, s = es.y;
      int pn = p0 + base + 4 + slot;
      int2 esn = (pn < p1) ? csr_es[pn] : make_int2(0, 0);
      float ea = (valid && q < 6) ? eattr[(size_t)e * 6 + q] : 0.f;
      float4 xls = valid ? *(const float4*)(xl + (size_t)s * 64 + q * 4)
                         : make_float4(0.f, 0.f, 0.f, 0.f);
      float m0 = xls.x + xr4.x, m1 = xls.y + xr4.y, m2 = xls.z + xr4.z, m3 = xls.w + xr4.w;
#pragma unroll
      for (int i = 0; i < 6; ++i) {
        float eai = __shfl(ea, sb + i);
        m0 = fmaf(eai, wef[i][0], m0);
        m1 = fmaf(eai, wef[i][1], m1);
        m2 = fmaf(eai, wef[i][2], m2);
        m3 = fmaf(eai, wef[i][3], m3);
      }
      m0 = (m0 > 0.f) ? m0 : 0.2f * m0;
      m1 = (m1 > 0.f) ? m1 : 0.2f * m1;
      m2 = (m2 > 0.f) ? m2 : 0.2f * m2;
      m3 = (m3 > 0.f) ? m3 : 0.2f * m3;
      float t = m0 * att4[0];
      t = fmaf(m1, att4[1], t);
      t = fmaf(m2, att4[2], t);
      t = fmaf(m3, att4[3], t);
      t += __shfl_xor(t, 1);
      t += __shfl_xor(t, 2);
      float ex = valid ? __expf(t) : 0.f;
      den += ex;
      num0 = fmaf(xls.x, ex, num0);
      num1 = fmaf(xls.y, ex, num1);
      num2 = fmaf(xls.z, ex, num2);
      num3 = fmaf(xls.w, ex, num3);
      int idx = base + slot;
      if (valid && idx < CAP) {
        if ((lane & 3) == 0) exbuf[wv][idx * 4 + head] = ex;
        if (q == 0) ebuf[wv][idx] = e;
      }
      es = esn;
    }
    num0 += __shfl_xor(num0, 16); num0 += __shfl_xor(num0, 32);
    num1 += __shfl_xor(num1, 16); num1 += __shfl_xor(num1, 32);
    num2 += __shfl_xor(num2, 16); num2 += __shfl_xor(num2, 32);
    num3 += __shfl_xor(num3, 16); num3 += __shfl_xor(num3, 32);
    den  += __shfl_xor(den, 16);  den  += __shfl_xor(den, 32);
    float dinv = 1.f / (den + 1e-16f);
    float o0 = fmaf(num0, dinv, b4[0]);
    float o1 = fmaf(num1, dinv, b4[1]);
    float o2 = fmaf(num2, dinv, b4[2]);
    float o3 = fmaf(num3, dinv, b4[3]);
    if (RELU) {
      o0 = fmaxf(o0, 0.f); o1 = fmaxf(o1, 0.f); o2 = fmaxf(o2, 0.f); o3 = fmaxf(o3, 0.f);
    }
    if (slot == 0)
      *(float4*)(hout + (size_t)v * 64 + q * 4) = make_float4(o0, o1, o2, o3);
    float dh = __shfl(dinv, (lane & 3) << 2);
    if (cnt <= CAP) {
      for (int base2 = 0; base2 < cnt; base2 += 16) {
        int idx = base2 + (lane >> 2);
        if (idx < cnt) {
          float exv = exbuf[wv][idx * 4 + (lane & 3)];
          int e = ebuf[wv][idx];
          alpha[(size_t)e * 4 + (lane & 3)] = exv * dh;
        }
      }
    } else {
      for (int pp = p0; pp < p1; ++pp) {
        int2 es2 = csr_es[pp];
        int e = es2.x, s = es2.y;
        float ea = (q < 6) ? eattr[(size_t)e * 6 + q] : 0.f;
        float4 xls = *(const float4*)(xl + (size_t)s * 64 + q * 4);
        float m0 = xls.x + xr4.x, m1 = xls.y + xr4.y, m2 = xls.z + xr4.z, m3 = xls.w + xr4.w;
#pragma unroll
        for (int i = 0; i < 6; ++i) {
          float eai = __shfl(ea, i);
          m0 = fmaf(eai, wef[i][0], m0);
          m1 = fmaf(eai, wef[i][1], m1);
          m2 = fmaf(eai, wef[i][2], m2);
          m3 = fmaf(eai, wef[i][3], m3);
        }
        m0 = (m0 > 0.f) ? m0 : 0.2f * m0;
        m1 = (m1 > 0.f) ? m1 : 0.2f * m1;
        m2 = (m2 > 0.f) ? m2 : 0.2f * m2;
        m3 = (m3 > 0.f) ? m3 : 0.2f * m3;
        float t = m0 * att4[0];
        t = fmaf(m1, att4[1], t);
        t = fmaf(m2, att4[2], t);
        t = fmaf(m3, att4[3], t);
        t += __shfl_xor(t, 1);
        t += __shfl_xor(t, 2);
        if (slot == 0 && (lane & 3) == 0)
          alpha[(size_t)e * 4 + head] = __expf(t) * dinv;
      }
    }
  }
}

extern "C" void kernel_launch(void* const* d_in, const int* in_sizes, int n_in,
                              void* d_out, int out_size, void* d_ws, size_t ws_size,
                              hipStream_t stream) {
  const float* x      = (const float*)d_in[0];
  const int* ntype    = (const int*)d_in[1];
  const int* sid      = (const int*)d_in[2];
  const int* ei       = (const int*)d_in[3];
  const float* eattr  = (const float*)d_in[4];
  const float* hs     = (const float*)d_in[5];
  const float* temb   = (const float*)d_in[6];
  const float* semb   = (const float*)d_in[7];
  const float* enc_w1 = (const float*)d_in[8];
  const float* enc_b1 = (const float*)d_in[9];
  const float* enc_w2 = (const float*)d_in[10];
  const float* enc_b2 = (const float*)d_in[11];
  const float* g1_wl  = (const float*)d_in[12];
  const float* g1_bl  = (const float*)d_in[13];
  const float* g1_wr  = (const float*)d_in[14];
  const float* g1_br  = (const float*)d_in[15];
  const float* g1_we  = (const float*)d_in[16];
  const float* g1_att = (const float*)d_in[17];
  const float* g1_bias= (const float*)d_in[18];
  const float* g2_wl  = (const float*)d_in[19];
  const float* g2_bl  = (const float*)d_in[20];
  const float* g2_wr  = (const float*)d_in[21];
  const float* g2_br  = (const float*)d_in[22];
  const float* g2_we  = (const float*)d_in[23];
  const float* g2_att = (const float*)d_in[24];
  const float* g2_bias= (const float*)d_in[25];
  const float* gru_wih= (const float*)d_in[26];
  const float* gru_bih= (const float*)d_in[27];
  const float* gru_whh= (const float*)d_in[28];
  const float* gru_bhh= (const float*)d_in[29];
  const float* dec_w1 = (const float*)d_in[30];
  const float* dec_b1 = (const float*)d_in[31];
  const float* dec_w2 = (const float*)d_in[32];
  const float* dec_b2 = (const float*)d_in[33];

  float* ws = (float*)d_ws;
  float* hA = ws;               // N*64
  float* hB = hA + N_ * 64;     // N*64  (gbuf = hB spans hB|xl|xr at GRU time)
  float* xl = hB + N_ * 64;     // N*64
  float* xr = xl + N_ * 64;     // N*64
  float* U  = xr + N_ * 64;     // N*64 (spare)
  int* deg  = (int*)(U + N_ * 64);   // N
  int* off  = deg + N_;              // N+1
  int* cur  = off + N_ + 1;          // N
  int* bsum = cur + N_;              // 64 (pad -> csr_es 8B aligned)
  int2* csr_es = (int2*)(bsum + 64); // E pairs

  float* gbuf = hB;   // N*192 spans hB|xl|xr

  float* out0  = (float*)d_out;      // N*7
  float* outnh = out0 + N_ * 7;      // N*64
  float* outa1 = outnh + N_ * 64;    // E*4
  float* outa2 = outa1 + E_ * 4;     // E*4

  const int NB_SCAN = (N_ + 1023) / 1024;  // 49
  const int NB_GEMM = (N_ + 127) / 128;    // 391

  hipMemsetAsync(deg, 0, N_ * sizeof(int), stream);
  k_hist<<<(E_ + 255) / 256, 256, 0, stream>>>(ei, deg);
  k_scan_blk<<<NB_SCAN, 1024, 0, stream>>>(deg, off, bsum);
  k_scan_top<<<1, 64, 0, stream>>>(bsum, NB_SCAN);
  k_scan_add<<<(N_ + 255) / 256, 256, 0, stream>>>(off, bsum, cur);
  k_scatter<<<(E_ + 255) / 256, 256, 0, stream>>>(ei, cur, csr_es);

  // Encoder
  k_gemm_enc<<<NB_GEMM, 256, 0, stream>>>(x, ntype, sid, temb, semb, enc_w1, enc_b1, hB);
  k_gemm64<<<NB_GEMM, 256, 0, stream>>>(hB, enc_w2, enc_b2, hA);
  // GAT layer 1: hA -> hB (relu)
  k_gemm2<<<NB_GEMM, 256, 0, stream>>>(hA, g1_wl, g1_bl, g1_wr, g1_br, xl, xr);
  k_fused<true><<<4096, 256, 0, stream>>>(off, csr_es, eattr, xl, xr,
                                          g1_we, g1_att, g1_bias, hB, outa1);
  // GAT layer 2: hB -> hA (no relu)
  k_gemm2<<<NB_GEMM, 256, 0, stream>>>(hB, g2_wl, g2_bl, g2_wr, g2_br, xl, xr);
  k_fused<false><<<4096, 256, 0, stream>>>(off, csr_es, eattr, xl, xr,
                                           g2_we, g2_att, g2_bias, hA, outa2);
  // GRU (gbuf overlays hB|xl|xr, all free now; reads hA / hs)
  k_gru_ih<<<NB_GEMM, 256, 0, stream>>>(hA, gru_wih, gru_bih, gbuf);
  k_gru_hh<<<NB_GEMM, 256, 0, stream>>>(hs, gru_whh, gru_bhh, gbuf, outnh);
  // Decoder (fused both layers)
  k_dec<<<NB_GEMM, 256, 0, stream>>>(outnh, dec_w1, dec_b1, dec_w2, dec_b2, out0);
}